// Round 6
// baseline (498.745 us; speedup 1.0000x reference)
//
#include <hip/hip_runtime.h>
#include <hip/hip_bf16.h>

typedef short short8 __attribute__((ext_vector_type(8)));
typedef float f32x16 __attribute__((ext_vector_type(16)));
typedef float f32x4 __attribute__((ext_vector_type(4)));
typedef float f32x2 __attribute__((ext_vector_type(2)));

// ---------- bf16 helpers ----------
__device__ __forceinline__ unsigned short f2bf(float f) {
  union { float f; unsigned int u; } v; v.f = f;
  unsigned int u = v.u;
  unsigned int r = u + 0x7FFFu + ((u >> 16) & 1u);
  return (unsigned short)(r >> 16);
}
__device__ __forceinline__ float bf2f(unsigned short s) {
  union { unsigned int u; float f; } v; v.u = ((unsigned int)s) << 16;
  return v.f;
}
__device__ __forceinline__ unsigned packbf2(float a, float b) {
  union { __hip_bfloat162 h; unsigned u; } cv;
  cv.h = __hip_bfloat162{__float2bfloat16(a), __float2bfloat16(b)};
  return cv.u;
}

// ---------- erf / GELU (A&S 7.1.25 3-term, |err| <= 2.5e-5) ----------
__device__ __forceinline__ float erfc_core(float u) {
  float e = __expf(-u * u);
  float d = fmaf(0.47047f, u, 1.0f);
  float r = __builtin_amdgcn_rcpf(d);
  float p = fmaf(0.7478556f, r, -0.0958798f);
  p = fmaf(p, r, 0.3480242f);
  p = p * r;
  return p * e;
}
// pair version: f32x2 arithmetic for v_pk_* formation; trans stays scalar
__device__ __forceinline__ f32x2 gelu2(f32x2 t) {
  f32x2 at; at[0] = fabsf(t[0]); at[1] = fabsf(t[1]);
  f32x2 u = at * 0.7071067811865475f;
  f32x2 e; e[0] = __expf(-u[0] * u[0]); e[1] = __expf(-u[1] * u[1]);
  f32x2 d = u * 0.47047f + 1.0f;
  f32x2 r; r[0] = __builtin_amdgcn_rcpf(d[0]); r[1] = __builtin_amdgcn_rcpf(d[1]);
  f32x2 p = r * 0.7478556f - 0.0958798f;
  p = p * r + 0.3480242f;
  p = p * r;
  f32x2 wv = p * e;
  f32x2 h = at * 0.5f;
  f32x2 res = t * 0.5f + h;
  return res - h * wv;
}

// ---------- per-(graph,channel) Taylor coeffs with W1 folded in ----------
__global__ void k_graph(const float* __restrict__ h, const float* __restrict__ W1,
                        const float* __restrict__ b1,
                        float* __restrict__ p0, float* __restrict__ q1,
                        float* __restrict__ q2) {
  __shared__ float hs[128];
  int g = blockIdx.x, c = threadIdx.x;
  if (c < 128) hs[c] = h[g * 128 + c];
  __syncthreads();
  float acc = b1[c];
#pragma unroll 8
  for (int k = 0; k < 128; k++)
    acc = fmaf(hs[k], W1[(1 + k) * 256 + c], acc);
  float w1c = W1[c];
  float t0 = fmaf(0.5f, w1c, acc);
  float u = fabsf(t0) * 0.7071067811865475f;
  float wq = erfc_core(u);
  float Phi = (t0 >= 0.f) ? fmaf(-0.5f, wq, 1.0f) : 0.5f * wq;
  float phi = 0.3989422804f * __expf(-0.5f * t0 * t0);
  int o = g * 256 + c;
  p0[o] = t0 * Phi;
  q1[o] = w1c * fmaf(t0, phi, Phi);
  q2[o] = (w1c * w1c) * (phi * fmaf(-0.5f * t0, t0, 1.0f));
}

// ---------- pack weights to per-lane MFMA A-fragments, bf16 hi+lo ----------
// W2 (32x32x16): frag ((ct*16+ks)*64+lane)*8+j ; k=ks*16+(lane>>5)*8+j ; ch=ct*32+(lane&31)
// W3 (16x16x32, K=256): frag ((ct*8+ks)*64+lane)*8+j ; k=ks*32+((lane>>4)&3)*8+j ; ch=ct*16+(lane&15)
__global__ void k_pack(const float* __restrict__ W2, const float* __restrict__ W3,
                       unsigned short* __restrict__ W2H, unsigned short* __restrict__ W2L,
                       unsigned short* __restrict__ A3H, unsigned short* __restrict__ A3L) {
  int tid = blockIdx.x * 256 + threadIdx.x;
  if (tid < 65536) {
    int j = tid & 7, lane = (tid >> 3) & 63, ks = (tid >> 9) & 15, ct = tid >> 13;
    int k = ks * 16 + ((lane >> 5) << 3) + j;
    int ch = ct * 32 + (lane & 31);
    float wv = W2[k * 256 + ch];
    unsigned short hi = f2bf(wv);
    W2H[tid] = hi; W2L[tid] = f2bf(wv - bf2f(hi));
  } else if (tid < 65536 + 16384) {
    int t3 = tid - 65536;
    int j = t3 & 7, lane = (t3 >> 3) & 63, ks = (t3 >> 9) & 7, ct = t3 >> 12;
    int k = ks * 32 + ((lane >> 4) & 3) * 8 + j;
    int ch = ct * 16 + (lane & 15);
    float wv = W3[k * 64 + ch];
    unsigned short hi = f2bf(wv);
    A3H[t3] = hi; A3L[t3] = f2bf(wv - bf2f(hi));
  }
}

// zbuf swizzle: byte = row*512 + (colbyte ^ ((row&7)<<4) ^ (((row>>3)&3)<<7))
// ---------- fused main: 64 nodes / 512 threads (8 waves) ----------
__global__ void __launch_bounds__(512, 8)
k_main(const float* __restrict__ x, const int* __restrict__ bidx,
       const float* __restrict__ p0, const float* __restrict__ q1,
       const float* __restrict__ q2,
       const unsigned short* __restrict__ W2H, const unsigned short* __restrict__ W2L,
       const unsigned short* __restrict__ A3H, const unsigned short* __restrict__ A3L,
       const float* __restrict__ b2, const float* __restrict__ b3,
       const float* __restrict__ W4, const float* __restrict__ b4,
       float* __restrict__ out, int N) {
  __shared__ unsigned short zbuf[64 * 256];  // 32 KB, z1 -> z2
  __shared__ float cf[3][512];               // 6 KB staged coeffs (2 graphs)
  __shared__ float ebuf[64][4];              // 1 KB per-node chtile partials

  const int t = threadIdx.x;
  const int w = t >> 6, l = t & 63;
  const int l31 = l & 31, lg = l >> 5, l7 = l & 7;
  const int base = blockIdx.x * 64;

  // stage Taylor coeffs for graphs gfirst, gfirst+1
  const int gfirst = bidx[min(base, N - 1)];
  {
    int s = t >> 8, c = t & 255;
    int gs = min(gfirst + s, 1023);
    cf[0][s * 256 + c] = p0[gs * 256 + c];
    cf[1][s * 256 + c] = q1[gs * 256 + c];
    cf[2][s * 256 + c] = q2[gs * 256 + c];
  }
  // node data: row = lane (coalesced)
  const int n = base + l;
  const bool valid = n < N;
  const float xv = valid ? x[n] : 0.0f;
  const int g = valid ? bidx[n] : gfirst;
  const float xm = xv - 0.5f;
  const int dg = g - gfirst;
  const int rswz = ((l & 7) << 4) ^ (((l >> 3) & 3) << 7);
  __syncthreads();

  // ---- L1: z1[l][c] = p0 + xm*(q1 + xm*q2); wave w owns channels [32w,32w+32) ----
  {
#pragma unroll
    for (int it = 0; it < 8; it++) {
      int c = w * 32 + it * 4;
      f32x4 a, q, s;
      if (dg <= 1) {
        a = *(const f32x4*)&cf[0][dg * 256 + c];
        q = *(const f32x4*)&cf[1][dg * 256 + c];
        s = *(const f32x4*)&cf[2][dg * 256 + c];
      } else {
        a = *(const f32x4*)(p0 + g * 256 + c);
        q = *(const f32x4*)(q1 + g * 256 + c);
        s = *(const f32x4*)(q2 + g * 256 + c);
      }
      float v0 = fmaf(xm, fmaf(xm, s[0], q[0]), a[0]);
      float v1 = fmaf(xm, fmaf(xm, s[1], q[1]), a[1]);
      float v2 = fmaf(xm, fmaf(xm, s[2], q[2]), a[2]);
      float v3 = fmaf(xm, fmaf(xm, s[3], q[3]), a[3]);
      int byte = l * 512 + ((c * 2) ^ rswz);
      *(uint2*)&zbuf[byte >> 1] = make_uint2(packbf2(v0, v1), packbf2(v2, v3));
    }
  }
  __syncthreads();

  // ---- L2: C[ch 256][node 64]; wave w -> chtile w; acc pre-init with b2 ----
  f32x16 acc[2];
  {
    const int cb = w * 32;
#pragma unroll
    for (int q = 0; q < 4; q++) {
      f32x4 bias = *(const f32x4*)(b2 + cb + 8 * q + 4 * lg);
#pragma unroll
      for (int i = 0; i < 4; i++) { acc[0][4 * q + i] = bias[i]; acc[1][4 * q + i] = bias[i]; }
    }
    const short8* w2h = (const short8*)W2H;
    const short8* w2l = (const short8*)W2L;
    const int fi = w * 1024 + l;
    const int bswz = (l7 << 4) ^ (((l31 >> 3) & 3) << 7);
#pragma unroll 2
    for (int ks = 0; ks < 16; ks++) {
      short8 ah = w2h[fi + ks * 64];
      short8 al = w2l[fi + ks * 64];
      int colx = (ks * 32 + lg * 16) ^ bswz;
      short8 b0 = *(const short8*)&zbuf[(l31 * 512 + colx) >> 1];
      short8 b1v = *(const short8*)&zbuf[((32 + l31) * 512 + colx) >> 1];
      acc[0] = __builtin_amdgcn_mfma_f32_32x32x16_bf16(ah, b0, acc[0], 0, 0, 0);
      acc[0] = __builtin_amdgcn_mfma_f32_32x32x16_bf16(al, b0, acc[0], 0, 0, 0);
      acc[1] = __builtin_amdgcn_mfma_f32_32x32x16_bf16(ah, b1v, acc[1], 0, 0, 0);
      acc[1] = __builtin_amdgcn_mfma_f32_32x32x16_bf16(al, b1v, acc[1], 0, 0, 0);
    }
  }
  __syncthreads();  // all waves done reading z1

  // ---- L2 epilogue: z2 = gelu(acc) -> bf16 LDS (same swizzled layout) ----
  {
    const int cb = w * 32;
#pragma unroll
    for (int q = 0; q < 4; q++) {
      int ch = cb + 8 * q + 4 * lg;
#pragma unroll
      for (int nt = 0; nt < 2; nt++) {
        int node = nt * 32 + l31;
        f32x2 ga = gelu2(f32x2{acc[nt][4 * q + 0], acc[nt][4 * q + 1]});
        f32x2 gb = gelu2(f32x2{acc[nt][4 * q + 2], acc[nt][4 * q + 3]});
        int byte = node * 512 + ((ch * 2) ^ ((node & 7) << 4) ^ (((node >> 3) & 3) << 7));
        *(uint2*)&zbuf[byte >> 1] = make_uint2(packbf2(ga[0], ga[1]), packbf2(gb[0], gb[1]));
      }
    }
  }
  __syncthreads();

  // ---- L3 (16x16x32, K=256): 16 tiles (ct 0..3 x nt 0..3); wave w -> tiles 2w, 2w+1 ----
  {
    const short8* a3h = (const short8*)A3H;
    const short8* a3l = (const short8*)A3L;
    const int lq = (l >> 4) & 3;   // lane quad-group
    const int l15 = l & 15;
#pragma unroll
    for (int p = 0; p < 2; p++) {
      const int tt = 2 * w + p;
      const int ct = tt >> 2, nt = tt & 3;
      const int node = nt * 16 + l15;
      const int bswz = ((node & 7) << 4) ^ (((node >> 3) & 3) << 7);
      f32x4 acc4 = *(const f32x4*)(b3 + ct * 16 + lq * 4);
#pragma unroll
      for (int ks = 0; ks < 8; ks++) {
        short8 ah = a3h[(ct * 8 + ks) * 64 + l];
        short8 al = a3l[(ct * 8 + ks) * 64 + l];
        int colx = (ks * 64 + lq * 16) ^ bswz;
        short8 bfr = *(const short8*)&zbuf[(node * 512 + colx) >> 1];
        acc4 = __builtin_amdgcn_mfma_f32_16x16x32_bf16(ah, bfr, acc4, 0, 0, 0);
        acc4 = __builtin_amdgcn_mfma_f32_16x16x32_bf16(al, bfr, acc4, 0, 0, 0);
      }
      // L4 partial: e = sum_i gelu(acc4[i]) * W4[ct*16+lq*4+i]
      f32x4 w4v = *(const f32x4*)(W4 + ct * 16 + lq * 4);
      f32x2 ga = gelu2(f32x2{acc4[0], acc4[1]});
      f32x2 gb = gelu2(f32x2{acc4[2], acc4[3]});
      float e = ga[0] * w4v[0] + ga[1] * w4v[1] + gb[0] * w4v[2] + gb[1] * w4v[3];
      e += __shfl_xor(e, 16, 64);
      e += __shfl_xor(e, 32, 64);   // e = full 16-ch (ct) sum for node, replicated
      if (l < 16) ebuf[node][ct] = e;
    }
  }
  __syncthreads();

  // ---- pool: wave 0 sums 4 chtile partials per node, segmented scan, atomic ----
  if (w == 0) {
    f32x4 ev = *(const f32x4*)ebuf[l];
    float e = (ev[0] + ev[1]) + (ev[2] + ev[3]) + b4[0];
    int gl = valid ? g : -1;
    if (!valid) e = 0.f;
#pragma unroll
    for (int d = 1; d < 64; d <<= 1) {
      float eo = __shfl_down(e, d, 64);
      int go = __shfl_down(gl, d, 64);
      if (l + d < 64 && go == gl) e += eo;
    }
    int gp = __shfl_up(gl, 1, 64);
    bool head = (l == 0) || (gp != gl);
    if (head && valid) atomicAdd(out + gl, e);
  }
}

extern "C" void kernel_launch(void* const* d_in, const int* in_sizes, int n_in,
                              void* d_out, int out_size, void* d_ws, size_t ws_size,
                              hipStream_t stream) {
  const float* x  = (const float*)d_in[0];
  const float* h  = (const float*)d_in[1];
  const int* bidx = (const int*)d_in[2];
  const float* W1 = (const float*)d_in[3];
  const float* b1 = (const float*)d_in[4];
  const float* W2 = (const float*)d_in[5];
  const float* b2 = (const float*)d_in[6];
  const float* W3 = (const float*)d_in[7];
  const float* b3 = (const float*)d_in[8];
  const float* W4 = (const float*)d_in[9];
  const float* b4 = (const float*)d_in[10];
  float* out = (float*)d_out;
  const int N = in_sizes[0];

  char* ws = (char*)d_ws;
  float* p0 = (float*)(ws);
  float* q1 = (float*)(ws + (1 << 20));
  float* q2 = (float*)(ws + (2 << 20));
  unsigned short* W2H = (unsigned short*)(ws + (3 << 20));
  unsigned short* W2L = (unsigned short*)(ws + (3 << 20) + 131072);
  unsigned short* A3H = (unsigned short*)(ws + (3 << 20) + 262144);
  unsigned short* A3L = (unsigned short*)(ws + (3 << 20) + 262144 + 32768);

  hipMemsetAsync(d_out, 0, (size_t)out_size * sizeof(float), stream);
  k_graph<<<1024, 256, 0, stream>>>(h, W1, b1, p0, q1, q2);
  k_pack<<<320, 256, 0, stream>>>(W2, W3, W2H, W2L, A3H, A3L);
  const int nb = (N + 63) / 64;
  k_main<<<nb, 512, 0, stream>>>(x, bidx, p0, q1, q2, W2H, W2L, A3H, A3L,
                                 b2, b3, W4, b4, out, N);
}

// Round 7
// 485.524 us; speedup vs baseline: 1.0272x; 1.0272x over previous
//
#include <hip/hip_runtime.h>
#include <hip/hip_bf16.h>

typedef short short8 __attribute__((ext_vector_type(8)));
typedef float f32x16 __attribute__((ext_vector_type(16)));
typedef float f32x4 __attribute__((ext_vector_type(4)));
typedef float f32x2 __attribute__((ext_vector_type(2)));

// ---------- bf16 helpers ----------
__device__ __forceinline__ unsigned short f2bf(float f) {
  union { float f; unsigned int u; } v; v.f = f;
  unsigned int u = v.u;
  unsigned int r = u + 0x7FFFu + ((u >> 16) & 1u);
  return (unsigned short)(r >> 16);
}
__device__ __forceinline__ float bf2f(unsigned short s) {
  union { unsigned int u; float f; } v; v.u = ((unsigned int)s) << 16;
  return v.f;
}
__device__ __forceinline__ unsigned packbf2(float a, float b) {
  union { __hip_bfloat162 h; unsigned u; } cv;
  cv.h = __hip_bfloat162{__float2bfloat16(a), __float2bfloat16(b)};
  return cv.u;
}

// ---------- erf / GELU (A&S 7.1.25 3-term, |err| <= 2.5e-5) ----------
__device__ __forceinline__ float erfc_core(float u) {
  float e = __expf(-u * u);
  float d = fmaf(0.47047f, u, 1.0f);
  float r = __builtin_amdgcn_rcpf(d);
  float p = fmaf(0.7478556f, r, -0.0958798f);
  p = fmaf(p, r, 0.3480242f);
  p = p * r;
  return p * e;
}
// pair version: f32x2 arithmetic for v_pk_* formation; trans stays scalar
__device__ __forceinline__ f32x2 gelu2(f32x2 t) {
  f32x2 at; at[0] = fabsf(t[0]); at[1] = fabsf(t[1]);
  f32x2 u = at * 0.7071067811865475f;
  f32x2 e; e[0] = __expf(-u[0] * u[0]); e[1] = __expf(-u[1] * u[1]);
  f32x2 d = u * 0.47047f + 1.0f;
  f32x2 r; r[0] = __builtin_amdgcn_rcpf(d[0]); r[1] = __builtin_amdgcn_rcpf(d[1]);
  f32x2 p = r * 0.7478556f - 0.0958798f;
  p = p * r + 0.3480242f;
  p = p * r;
  f32x2 wv = p * e;
  f32x2 h = at * 0.5f;
  f32x2 res = t * 0.5f + h;
  return res - h * wv;
}

// ---------- fused prep: Taylor coeffs (blocks 0..1023) + weight packing ----------
// W2 (32x32x16): frag ((ct*16+ks)*64+lane)*8+j ; k=ks*16+(lane>>5)*8+j ; ch=ct*32+(lane&31)
// W3 (16x16x32, K=256): frag ((ct*8+ks)*64+lane)*8+j ; k=ks*32+((lane>>4)&3)*8+j ; ch=ct*16+(lane&15)
__global__ void k_prep(const float* __restrict__ h, const float* __restrict__ W1,
                       const float* __restrict__ b1,
                       const float* __restrict__ W2, const float* __restrict__ W3,
                       float* __restrict__ p0, float* __restrict__ q1,
                       float* __restrict__ q2,
                       unsigned short* __restrict__ W2H, unsigned short* __restrict__ W2L,
                       unsigned short* __restrict__ A3H, unsigned short* __restrict__ A3L) {
  if (blockIdx.x < 1024) {
    __shared__ float hs[128];
    int g = blockIdx.x, c = threadIdx.x;
    if (c < 128) hs[c] = h[g * 128 + c];
    __syncthreads();
    float acc = b1[c];
#pragma unroll 8
    for (int k = 0; k < 128; k++)
      acc = fmaf(hs[k], W1[(1 + k) * 256 + c], acc);
    float w1c = W1[c];
    float t0 = fmaf(0.5f, w1c, acc);
    float u = fabsf(t0) * 0.7071067811865475f;
    float wq = erfc_core(u);
    float Phi = (t0 >= 0.f) ? fmaf(-0.5f, wq, 1.0f) : 0.5f * wq;
    float phi = 0.3989422804f * __expf(-0.5f * t0 * t0);
    int o = g * 256 + c;
    p0[o] = t0 * Phi;
    q1[o] = w1c * fmaf(t0, phi, Phi);
    q2[o] = (w1c * w1c) * (phi * fmaf(-0.5f * t0, t0, 1.0f));
    return;
  }
  int tid = (blockIdx.x - 1024) * 256 + threadIdx.x;
  if (tid < 65536) {
    int j = tid & 7, lane = (tid >> 3) & 63, ks = (tid >> 9) & 15, ct = tid >> 13;
    int k = ks * 16 + ((lane >> 5) << 3) + j;
    int ch = ct * 32 + (lane & 31);
    float wv = W2[k * 256 + ch];
    unsigned short hi = f2bf(wv);
    W2H[tid] = hi; W2L[tid] = f2bf(wv - bf2f(hi));
  } else if (tid < 65536 + 16384) {
    int t3 = tid - 65536;
    int j = t3 & 7, lane = (t3 >> 3) & 63, ks = (t3 >> 9) & 7, ct = t3 >> 12;
    int k = ks * 32 + ((lane >> 4) & 3) * 8 + j;
    int ch = ct * 16 + (lane & 15);
    float wv = W3[k * 64 + ch];
    unsigned short hi = f2bf(wv);
    A3H[t3] = hi; A3L[t3] = f2bf(wv - bf2f(hi));
  }
}

// zbuf swizzle: byte = row*512 + (colbyte ^ ((row&7)<<4) ^ (((row>>3)&3)<<7))
// ---------- fused main: 64 nodes / 512 threads (8 waves) ----------
// launch_bounds(512,7): 72-reg budget; peak demand ~68 (32 arch + 32 AGPR + L3 temps)
// at (512,8)=64 the compiler spilled ~100 MB of scratch (round-6 WRITE_SIZE).
__global__ void __launch_bounds__(512, 7)
k_main(const float* __restrict__ x, const int* __restrict__ bidx,
       const float* __restrict__ p0, const float* __restrict__ q1,
       const float* __restrict__ q2,
       const unsigned short* __restrict__ W2H, const unsigned short* __restrict__ W2L,
       const unsigned short* __restrict__ A3H, const unsigned short* __restrict__ A3L,
       const float* __restrict__ b2, const float* __restrict__ b3,
       const float* __restrict__ W4, const float* __restrict__ b4,
       float* __restrict__ out, int N) {
  __shared__ unsigned short zbuf[64 * 256];  // 32 KB, z1 -> z2
  __shared__ float cf[3][512];               // 6 KB staged coeffs (2 graphs)
  __shared__ float ebuf[64][4];              // 1 KB per-node chtile partials

  const int t = threadIdx.x;
  const int w = t >> 6, l = t & 63;
  const int l31 = l & 31, lg = l >> 5, l7 = l & 7;
  const int base = blockIdx.x * 64;

  // stage Taylor coeffs for graphs gfirst, gfirst+1
  const int gfirst = bidx[min(base, N - 1)];
  {
    int s = t >> 8, c = t & 255;
    int gs = min(gfirst + s, 1023);
    cf[0][s * 256 + c] = p0[gs * 256 + c];
    cf[1][s * 256 + c] = q1[gs * 256 + c];
    cf[2][s * 256 + c] = q2[gs * 256 + c];
  }
  // node data: row = lane (coalesced)
  const int n = base + l;
  const bool valid = n < N;
  const float xv = valid ? x[n] : 0.0f;
  const int g = valid ? bidx[n] : gfirst;
  const float xm = xv - 0.5f;
  const int dg = g - gfirst;
  const int rswz = ((l & 7) << 4) ^ (((l >> 3) & 3) << 7);
  __syncthreads();

  // ---- L1: z1[l][c] = p0 + xm*(q1 + xm*q2); wave w owns channels [32w,32w+32) ----
  {
#pragma unroll
    for (int it = 0; it < 8; it++) {
      int c = w * 32 + it * 4;
      f32x4 a, q, s;
      if (dg <= 1) {
        a = *(const f32x4*)&cf[0][dg * 256 + c];
        q = *(const f32x4*)&cf[1][dg * 256 + c];
        s = *(const f32x4*)&cf[2][dg * 256 + c];
      } else {
        a = *(const f32x4*)(p0 + g * 256 + c);
        q = *(const f32x4*)(q1 + g * 256 + c);
        s = *(const f32x4*)(q2 + g * 256 + c);
      }
      float v0 = fmaf(xm, fmaf(xm, s[0], q[0]), a[0]);
      float v1 = fmaf(xm, fmaf(xm, s[1], q[1]), a[1]);
      float v2 = fmaf(xm, fmaf(xm, s[2], q[2]), a[2]);
      float v3 = fmaf(xm, fmaf(xm, s[3], q[3]), a[3]);
      int byte = l * 512 + ((c * 2) ^ rswz);
      *(uint2*)&zbuf[byte >> 1] = make_uint2(packbf2(v0, v1), packbf2(v2, v3));
    }
  }
  __syncthreads();

  // ---- L2: C[ch 256][node 64]; wave w -> chtile w; acc pre-init with b2 ----
  f32x16 acc[2];
  {
    const int cb = w * 32;
#pragma unroll
    for (int q = 0; q < 4; q++) {
      f32x4 bias = *(const f32x4*)(b2 + cb + 8 * q + 4 * lg);
#pragma unroll
      for (int i = 0; i < 4; i++) { acc[0][4 * q + i] = bias[i]; acc[1][4 * q + i] = bias[i]; }
    }
    const short8* w2h = (const short8*)W2H;
    const short8* w2l = (const short8*)W2L;
    const int fi = w * 1024 + l;
    const int bswz = (l7 << 4) ^ (((l31 >> 3) & 3) << 7);
#pragma unroll 2
    for (int ks = 0; ks < 16; ks++) {
      short8 ah = w2h[fi + ks * 64];
      short8 al = w2l[fi + ks * 64];
      int colx = (ks * 32 + lg * 16) ^ bswz;
      short8 b0 = *(const short8*)&zbuf[(l31 * 512 + colx) >> 1];
      short8 b1v = *(const short8*)&zbuf[((32 + l31) * 512 + colx) >> 1];
      acc[0] = __builtin_amdgcn_mfma_f32_32x32x16_bf16(ah, b0, acc[0], 0, 0, 0);
      acc[0] = __builtin_amdgcn_mfma_f32_32x32x16_bf16(al, b0, acc[0], 0, 0, 0);
      acc[1] = __builtin_amdgcn_mfma_f32_32x32x16_bf16(ah, b1v, acc[1], 0, 0, 0);
      acc[1] = __builtin_amdgcn_mfma_f32_32x32x16_bf16(al, b1v, acc[1], 0, 0, 0);
    }
  }
  __syncthreads();  // all waves done reading z1

  // ---- L2 epilogue: z2 = gelu(acc) -> bf16 LDS (same swizzled layout) ----
  {
    const int cb = w * 32;
#pragma unroll
    for (int q = 0; q < 4; q++) {
      int ch = cb + 8 * q + 4 * lg;
#pragma unroll
      for (int nt = 0; nt < 2; nt++) {
        int node = nt * 32 + l31;
        f32x2 ga = gelu2(f32x2{acc[nt][4 * q + 0], acc[nt][4 * q + 1]});
        f32x2 gb = gelu2(f32x2{acc[nt][4 * q + 2], acc[nt][4 * q + 3]});
        int byte = node * 512 + ((ch * 2) ^ ((node & 7) << 4) ^ (((node >> 3) & 3) << 7));
        *(uint2*)&zbuf[byte >> 1] = make_uint2(packbf2(ga[0], ga[1]), packbf2(gb[0], gb[1]));
      }
    }
  }
  __syncthreads();

  // ---- L3 (16x16x32, K=256): 16 tiles (ct 0..3 x nt 0..3); wave w -> tiles 2w, 2w+1 ----
  {
    const short8* a3h = (const short8*)A3H;
    const short8* a3l = (const short8*)A3L;
    const int lq = (l >> 4) & 3;   // lane quad-group
    const int l15 = l & 15;
#pragma unroll
    for (int p = 0; p < 2; p++) {
      const int tt = 2 * w + p;
      const int ct = tt >> 2, nt = tt & 3;
      const int node = nt * 16 + l15;
      const int bswz = ((node & 7) << 4) ^ (((node >> 3) & 3) << 7);
      f32x4 acc4 = *(const f32x4*)(b3 + ct * 16 + lq * 4);
#pragma unroll
      for (int ks = 0; ks < 8; ks++) {
        short8 ah = a3h[(ct * 8 + ks) * 64 + l];
        short8 al = a3l[(ct * 8 + ks) * 64 + l];
        int colx = (ks * 64 + lq * 16) ^ bswz;
        short8 bfr = *(const short8*)&zbuf[(node * 512 + colx) >> 1];
        acc4 = __builtin_amdgcn_mfma_f32_16x16x32_bf16(ah, bfr, acc4, 0, 0, 0);
        acc4 = __builtin_amdgcn_mfma_f32_16x16x32_bf16(al, bfr, acc4, 0, 0, 0);
      }
      // L4 partial: e = sum_i gelu(acc4[i]) * W4[ct*16+lq*4+i]
      f32x4 w4v = *(const f32x4*)(W4 + ct * 16 + lq * 4);
      f32x2 ga = gelu2(f32x2{acc4[0], acc4[1]});
      f32x2 gb = gelu2(f32x2{acc4[2], acc4[3]});
      float e = ga[0] * w4v[0] + ga[1] * w4v[1] + gb[0] * w4v[2] + gb[1] * w4v[3];
      e += __shfl_xor(e, 16, 64);
      e += __shfl_xor(e, 32, 64);   // e = full 16-ch (ct) sum for node, replicated
      if (l < 16) ebuf[node][ct] = e;
    }
  }
  __syncthreads();

  // ---- pool: wave 0 sums 4 chtile partials per node, segmented scan, atomic ----
  if (w == 0) {
    f32x4 ev = *(const f32x4*)ebuf[l];
    float e = (ev[0] + ev[1]) + (ev[2] + ev[3]) + b4[0];
    int gl = valid ? g : -1;
    if (!valid) e = 0.f;
#pragma unroll
    for (int d = 1; d < 64; d <<= 1) {
      float eo = __shfl_down(e, d, 64);
      int go = __shfl_down(gl, d, 64);
      if (l + d < 64 && go == gl) e += eo;
    }
    int gp = __shfl_up(gl, 1, 64);
    bool head = (l == 0) || (gp != gl);
    if (head && valid) atomicAdd(out + gl, e);
  }
}

extern "C" void kernel_launch(void* const* d_in, const int* in_sizes, int n_in,
                              void* d_out, int out_size, void* d_ws, size_t ws_size,
                              hipStream_t stream) {
  const float* x  = (const float*)d_in[0];
  const float* h  = (const float*)d_in[1];
  const int* bidx = (const int*)d_in[2];
  const float* W1 = (const float*)d_in[3];
  const float* b1 = (const float*)d_in[4];
  const float* W2 = (const float*)d_in[5];
  const float* b2 = (const float*)d_in[6];
  const float* W3 = (const float*)d_in[7];
  const float* b3 = (const float*)d_in[8];
  const float* W4 = (const float*)d_in[9];
  const float* b4 = (const float*)d_in[10];
  float* out = (float*)d_out;
  const int N = in_sizes[0];

  char* ws = (char*)d_ws;
  float* p0 = (float*)(ws);
  float* q1 = (float*)(ws + (1 << 20));
  float* q2 = (float*)(ws + (2 << 20));
  unsigned short* W2H = (unsigned short*)(ws + (3 << 20));
  unsigned short* W2L = (unsigned short*)(ws + (3 << 20) + 131072);
  unsigned short* A3H = (unsigned short*)(ws + (3 << 20) + 262144);
  unsigned short* A3L = (unsigned short*)(ws + (3 << 20) + 262144 + 32768);

  hipMemsetAsync(d_out, 0, (size_t)out_size * sizeof(float), stream);
  k_prep<<<1344, 256, 0, stream>>>(h, W1, b1, W2, W3, p0, q1, q2, W2H, W2L, A3H, A3L);
  const int nb = (N + 63) / 64;
  k_main<<<nb, 512, 0, stream>>>(x, bidx, p0, q1, q2, W2H, W2L, A3H, A3L,
                                 b2, b3, W4, b4, out, N);
}

// Round 8
// 460.442 us; speedup vs baseline: 1.0832x; 1.0545x over previous
//
#include <hip/hip_runtime.h>
#include <hip/hip_bf16.h>

typedef short short8 __attribute__((ext_vector_type(8)));
typedef float f32x16 __attribute__((ext_vector_type(16)));
typedef float f32x4 __attribute__((ext_vector_type(4)));
typedef float f32x2 __attribute__((ext_vector_type(2)));

// ---------- bf16 helpers ----------
__device__ __forceinline__ unsigned short f2bf(float f) {
  union { float f; unsigned int u; } v; v.f = f;
  unsigned int u = v.u;
  unsigned int r = u + 0x7FFFu + ((u >> 16) & 1u);
  return (unsigned short)(r >> 16);
}
__device__ __forceinline__ float bf2f(unsigned short s) {
  union { unsigned int u; float f; } v; v.u = ((unsigned int)s) << 16;
  return v.f;
}
__device__ __forceinline__ unsigned packbf2(float a, float b) {
  union { __hip_bfloat162 h; unsigned u; } cv;
  cv.h = __hip_bfloat162{__float2bfloat16(a), __float2bfloat16(b)};
  return cv.u;
}

// ---------- erf / GELU (A&S 7.1.25 3-term, |err| <= 2.5e-5) ----------
__device__ __forceinline__ float erfc_core(float u) {
  float e = __expf(-u * u);
  float d = fmaf(0.47047f, u, 1.0f);
  float r = __builtin_amdgcn_rcpf(d);
  float p = fmaf(0.7478556f, r, -0.0958798f);
  p = fmaf(p, r, 0.3480242f);
  p = p * r;
  return p * e;
}
// pair version: f32x2 arithmetic for v_pk_* formation; trans stays scalar
__device__ __forceinline__ f32x2 gelu2(f32x2 t) {
  f32x2 at; at[0] = fabsf(t[0]); at[1] = fabsf(t[1]);
  f32x2 u = at * 0.7071067811865475f;
  f32x2 e; e[0] = __expf(-u[0] * u[0]); e[1] = __expf(-u[1] * u[1]);
  f32x2 d = u * 0.47047f + 1.0f;
  f32x2 r; r[0] = __builtin_amdgcn_rcpf(d[0]); r[1] = __builtin_amdgcn_rcpf(d[1]);
  f32x2 p = r * 0.7478556f - 0.0958798f;
  p = p * r + 0.3480242f;
  p = p * r;
  f32x2 wv = p * e;
  f32x2 h = at * 0.5f;
  f32x2 res = t * 0.5f + h;
  return res - h * wv;
}

// ---------- fused prep: Taylor coeffs (blocks 0..1023) + weight packing ----------
// W2 (32x32x16): frag ((ct*16+ks)*64+lane)*8+j ; k=ks*16+(lane>>5)*8+j ; ch=ct*32+(lane&31)
// W3 (16x16x32, K=256): frag ((ct*8+ks)*64+lane)*8+j ; k=ks*32+((lane>>4)&3)*8+j ; ch=ct*16+(lane&15)
__global__ void k_prep(const float* __restrict__ h, const float* __restrict__ W1,
                       const float* __restrict__ b1,
                       const float* __restrict__ W2, const float* __restrict__ W3,
                       float* __restrict__ p0, float* __restrict__ q1,
                       float* __restrict__ q2,
                       unsigned short* __restrict__ W2H, unsigned short* __restrict__ W2L,
                       unsigned short* __restrict__ A3H, unsigned short* __restrict__ A3L) {
  if (blockIdx.x < 1024) {
    __shared__ float hs[128];
    int g = blockIdx.x, c = threadIdx.x;
    if (c < 128) hs[c] = h[g * 128 + c];
    __syncthreads();
    float acc = b1[c];
#pragma unroll 8
    for (int k = 0; k < 128; k++)
      acc = fmaf(hs[k], W1[(1 + k) * 256 + c], acc);
    float w1c = W1[c];
    float t0 = fmaf(0.5f, w1c, acc);
    float u = fabsf(t0) * 0.7071067811865475f;
    float wq = erfc_core(u);
    float Phi = (t0 >= 0.f) ? fmaf(-0.5f, wq, 1.0f) : 0.5f * wq;
    float phi = 0.3989422804f * __expf(-0.5f * t0 * t0);
    int o = g * 256 + c;
    p0[o] = t0 * Phi;
    q1[o] = w1c * fmaf(t0, phi, Phi);
    q2[o] = (w1c * w1c) * (phi * fmaf(-0.5f * t0, t0, 1.0f));
    return;
  }
  int tid = (blockIdx.x - 1024) * 256 + threadIdx.x;
  if (tid < 65536) {
    int j = tid & 7, lane = (tid >> 3) & 63, ks = (tid >> 9) & 15, ct = tid >> 13;
    int k = ks * 16 + ((lane >> 5) << 3) + j;
    int ch = ct * 32 + (lane & 31);
    float wv = W2[k * 256 + ch];
    unsigned short hi = f2bf(wv);
    W2H[tid] = hi; W2L[tid] = f2bf(wv - bf2f(hi));
  } else if (tid < 65536 + 16384) {
    int t3 = tid - 65536;
    int j = t3 & 7, lane = (t3 >> 3) & 63, ks = (t3 >> 9) & 7, ct = t3 >> 12;
    int k = ks * 32 + ((lane >> 4) & 3) * 8 + j;
    int ch = ct * 16 + (lane & 15);
    float wv = W3[k * 64 + ch];
    unsigned short hi = f2bf(wv);
    A3H[t3] = hi; A3L[t3] = f2bf(wv - bf2f(hi));
  }
}

// zbuf swizzle: byte = row*512 + (colbyte ^ ((row&7)<<4) ^ (((row>>3)&3)<<7))
// ---------- fused main: 64 nodes / 512 threads (8 waves) ----------
// launch_bounds(512,6): 85-reg budget. Blocks/CU is 3 either way (7 or 6
// waves/SIMD quota -> floor(quota*4/8)=3); 6 frees +13 regs for pipelining.
__global__ void __launch_bounds__(512, 6)
k_main(const float* __restrict__ x, const int* __restrict__ bidx,
       const float* __restrict__ p0, const float* __restrict__ q1,
       const float* __restrict__ q2,
       const unsigned short* __restrict__ W2H, const unsigned short* __restrict__ W2L,
       const unsigned short* __restrict__ A3H, const unsigned short* __restrict__ A3L,
       const float* __restrict__ b2, const float* __restrict__ b3,
       const float* __restrict__ W4, const float* __restrict__ b4,
       float* __restrict__ out, int N) {
  __shared__ unsigned short zbuf[64 * 256];  // 32 KB, z1 -> z2
  __shared__ float ebuf[64][4];              // 1 KB per-node chtile partials

  const int t = threadIdx.x;
  const int w = t >> 6, l = t & 63;
  const int l31 = l & 31, lg = l >> 5, l7 = l & 7;
  const int base = blockIdx.x * 64;

  const short8* w2h = (const short8*)W2H;
  const short8* w2l = (const short8*)W2L;
  const int fi = w * 1024 + l;
  // issue first L2 A-fragment loads early (in flight across all of L1)
  short8 ah = w2h[fi], al = w2l[fi];

  // node data: row = lane (coalesced)
  const int n = base + l;
  const bool valid = n < N;
  const float xv = valid ? x[n] : 0.0f;
  const int g = valid ? bidx[n] : 0;
  const float xm = xv - 0.5f;
  const int rswz = ((l & 7) << 4) ^ (((l >> 3) & 3) << 7);

  // ---- L1: z1[l][c] = p0 + xm*(q1 + xm*q2); wave w owns channels [32w,32w+32) ----
  // coeffs read straight from L2$ (<= 3 distinct graphs per wave -> few lines)
  {
    const float* P0 = p0 + g * 256;
    const float* Q1 = q1 + g * 256;
    const float* Q2 = q2 + g * 256;
#pragma unroll 2
    for (int it = 0; it < 8; it++) {
      int c = w * 32 + it * 4;
      f32x4 a = *(const f32x4*)(P0 + c);
      f32x4 q = *(const f32x4*)(Q1 + c);
      f32x4 s = *(const f32x4*)(Q2 + c);
      float v0 = fmaf(xm, fmaf(xm, s[0], q[0]), a[0]);
      float v1 = fmaf(xm, fmaf(xm, s[1], q[1]), a[1]);
      float v2 = fmaf(xm, fmaf(xm, s[2], q[2]), a[2]);
      float v3 = fmaf(xm, fmaf(xm, s[3], q[3]), a[3]);
      int byte = l * 512 + ((c * 2) ^ rswz);
      *(uint2*)&zbuf[byte >> 1] = make_uint2(packbf2(v0, v1), packbf2(v2, v3));
    }
  }
  __syncthreads();

  // ---- L2: C[ch 256][node 64]; wave w -> chtile w; 1-deep A prefetch ----
  f32x16 acc[2];
  {
    const int cb = w * 32;
#pragma unroll
    for (int q = 0; q < 4; q++) {
      f32x4 bias = *(const f32x4*)(b2 + cb + 8 * q + 4 * lg);
#pragma unroll
      for (int i = 0; i < 4; i++) { acc[0][4 * q + i] = bias[i]; acc[1][4 * q + i] = bias[i]; }
    }
    const int bswz = (l7 << 4) ^ (((l31 >> 3) & 3) << 7);
#pragma unroll
    for (int ks = 0; ks < 16; ks++) {
      short8 ah_n, al_n;
      if (ks < 15) { ah_n = w2h[fi + (ks + 1) * 64]; al_n = w2l[fi + (ks + 1) * 64]; }
      int colx = (ks * 32 + lg * 16) ^ bswz;
      short8 b0 = *(const short8*)&zbuf[(l31 * 512 + colx) >> 1];
      short8 b1v = *(const short8*)&zbuf[((32 + l31) * 512 + colx) >> 1];
      acc[0] = __builtin_amdgcn_mfma_f32_32x32x16_bf16(ah, b0, acc[0], 0, 0, 0);
      acc[1] = __builtin_amdgcn_mfma_f32_32x32x16_bf16(ah, b1v, acc[1], 0, 0, 0);
      acc[0] = __builtin_amdgcn_mfma_f32_32x32x16_bf16(al, b0, acc[0], 0, 0, 0);
      acc[1] = __builtin_amdgcn_mfma_f32_32x32x16_bf16(al, b1v, acc[1], 0, 0, 0);
      ah = ah_n; al = al_n;
    }
  }
  __syncthreads();  // all waves done reading z1

  // ---- L2 epilogue: z2 = gelu(acc) -> bf16 LDS (same swizzled layout) ----
  {
    const int cb = w * 32;
#pragma unroll
    for (int q = 0; q < 4; q++) {
      int ch = cb + 8 * q + 4 * lg;
#pragma unroll
      for (int nt = 0; nt < 2; nt++) {
        int node = nt * 32 + l31;
        f32x2 ga = gelu2(f32x2{acc[nt][4 * q + 0], acc[nt][4 * q + 1]});
        f32x2 gb = gelu2(f32x2{acc[nt][4 * q + 2], acc[nt][4 * q + 3]});
        int byte = node * 512 + ((ch * 2) ^ ((node & 7) << 4) ^ (((node >> 3) & 3) << 7));
        *(uint2*)&zbuf[byte >> 1] = make_uint2(packbf2(ga[0], ga[1]), packbf2(gb[0], gb[1]));
      }
    }
  }
  __syncthreads();

  // ---- L3 (16x16x32, K=256): 16 tiles (ct 0..3 x nt 0..3); wave w -> tiles 2w, 2w+1 ----
  {
    const short8* a3h = (const short8*)A3H;
    const short8* a3l = (const short8*)A3L;
    const int lq = (l >> 4) & 3;   // lane quad-group
    const int l15 = l & 15;
#pragma unroll
    for (int p = 0; p < 2; p++) {
      const int tt = 2 * w + p;
      const int ct = tt >> 2, nt = tt & 3;
      const int node = nt * 16 + l15;
      const int bswz = ((node & 7) << 4) ^ (((node >> 3) & 3) << 7);
      f32x4 acc4 = *(const f32x4*)(b3 + ct * 16 + lq * 4);
      short8 a3 = a3h[(ct * 8) * 64 + l];
      short8 a3lo = a3l[(ct * 8) * 64 + l];
#pragma unroll
      for (int ks = 0; ks < 8; ks++) {
        short8 a3_n, a3lo_n;
        if (ks < 7) { a3_n = a3h[(ct * 8 + ks + 1) * 64 + l]; a3lo_n = a3l[(ct * 8 + ks + 1) * 64 + l]; }
        int colx = (ks * 64 + lq * 16) ^ bswz;
        short8 bfr = *(const short8*)&zbuf[(node * 512 + colx) >> 1];
        acc4 = __builtin_amdgcn_mfma_f32_16x16x32_bf16(a3, bfr, acc4, 0, 0, 0);
        acc4 = __builtin_amdgcn_mfma_f32_16x16x32_bf16(a3lo, bfr, acc4, 0, 0, 0);
        a3 = a3_n; a3lo = a3lo_n;
      }
      // L4 partial: e = sum_i gelu(acc4[i]) * W4[ct*16+lq*4+i]
      f32x4 w4v = *(const f32x4*)(W4 + ct * 16 + lq * 4);
      f32x2 ga = gelu2(f32x2{acc4[0], acc4[1]});
      f32x2 gb = gelu2(f32x2{acc4[2], acc4[3]});
      float e = ga[0] * w4v[0] + ga[1] * w4v[1] + gb[0] * w4v[2] + gb[1] * w4v[3];
      e += __shfl_xor(e, 16, 64);
      e += __shfl_xor(e, 32, 64);   // e = full 16-ch (ct) sum for node, replicated
      if (l < 16) ebuf[node][ct] = e;
    }
  }
  __syncthreads();

  // ---- pool: wave 0 sums 4 chtile partials per node, segmented scan, atomic ----
  if (w == 0) {
    f32x4 ev = *(const f32x4*)ebuf[l];
    float e = (ev[0] + ev[1]) + (ev[2] + ev[3]) + b4[0];
    int gl = valid ? g : -1;
    if (!valid) e = 0.f;
#pragma unroll
    for (int d = 1; d < 64; d <<= 1) {
      float eo = __shfl_down(e, d, 64);
      int go = __shfl_down(gl, d, 64);
      if (l + d < 64 && go == gl) e += eo;
    }
    int gp = __shfl_up(gl, 1, 64);
    bool head = (l == 0) || (gp != gl);
    if (head && valid) atomicAdd(out + gl, e);
  }
}

extern "C" void kernel_launch(void* const* d_in, const int* in_sizes, int n_in,
                              void* d_out, int out_size, void* d_ws, size_t ws_size,
                              hipStream_t stream) {
  const float* x  = (const float*)d_in[0];
  const float* h  = (const float*)d_in[1];
  const int* bidx = (const int*)d_in[2];
  const float* W1 = (const float*)d_in[3];
  const float* b1 = (const float*)d_in[4];
  const float* W2 = (const float*)d_in[5];
  const float* b2 = (const float*)d_in[6];
  const float* W3 = (const float*)d_in[7];
  const float* b3 = (const float*)d_in[8];
  const float* W4 = (const float*)d_in[9];
  const float* b4 = (const float*)d_in[10];
  float* out = (float*)d_out;
  const int N = in_sizes[0];

  char* ws = (char*)d_ws;
  float* p0 = (float*)(ws);
  float* q1 = (float*)(ws + (1 << 20));
  float* q2 = (float*)(ws + (2 << 20));
  unsigned short* W2H = (unsigned short*)(ws + (3 << 20));
  unsigned short* W2L = (unsigned short*)(ws + (3 << 20) + 131072);
  unsigned short* A3H = (unsigned short*)(ws + (3 << 20) + 262144);
  unsigned short* A3L = (unsigned short*)(ws + (3 << 20) + 262144 + 32768);

  hipMemsetAsync(d_out, 0, (size_t)out_size * sizeof(float), stream);
  k_prep<<<1344, 256, 0, stream>>>(h, W1, b1, W2, W3, p0, q1, q2, W2H, W2L, A3H, A3L);
  const int nb = (N + 63) / 64;
  k_main<<<nb, 512, 0, stream>>>(x, bidx, p0, q1, q2, W2H, W2L, A3H, A3L,
                                 b2, b3, W4, b4, out, N);
}